// Round 1
// baseline (456.902 us; speedup 1.0000x reference)
//
#include <hip/hip_runtime.h>
#include <cstdint>

#define NROW 6144
#define KDIM 128
#define NLAB 200
#define C_COEF (-0.28719499063341177f)   /* -ln(99)/16 ; A_COEF = 2 exactly */
#define UBV 64.0f

typedef _Float16 f16x8 __attribute__((ext_vector_type(8)));
typedef float f32x4 __attribute__((ext_vector_type(4)));
typedef __attribute__((address_space(1))) const void as1c_void;
typedef __attribute__((address_space(3))) void as3_void;

__device__ __forceinline__ unsigned key_of(float v){
  unsigned b = __float_as_uint(v);
  return (b & 0x80000000u) ? ~b : (b | 0x80000000u);
}
__device__ __forceinline__ float key_dec(unsigned k){
  unsigned b = (k & 0x80000000u) ? (k ^ 0x80000000u) : ~k;
  return __uint_as_float(b);
}
__device__ __forceinline__ float softplus_f(float x){
  return fmaxf(x, 0.f) + __logf(1.f + __expf(-fabsf(x)));
}
__device__ __forceinline__ float waveRedF(float v){
#pragma unroll
  for (int o = 32; o; o >>= 1) v += __shfl_down(v, o, 64);
  return v;
}

// ---------------- labels + per-label histogram ----------------
__global__ void k_label(const int* __restrict__ y, unsigned char* __restrict__ lab,
                        int* __restrict__ cnt){
  const int row = blockIdx.x;
  const int t = threadIdx.x;
  if (t < NLAB){
    if (y[(size_t)row * NLAB + t] != 0){
      lab[row] = (unsigned char)t;
      atomicAdd(&cnt[t], 1);
    }
  }
}

// ---------------- tanh -> swizzled f16, + quantization-loss partial ----------------
// uhswz[R][h*8 + j] = tanh(u[R][(h ^ (R&7))*8 + j])   (16B-group XOR swizzle)
__global__ __launch_bounds__(256) void k_tanh(const float* __restrict__ u,
    _Float16* __restrict__ uhswz, float* __restrict__ accf){
  const int tid = threadIdx.x;
  const int gid = blockIdx.x * 256 + tid;
  const int row = gid >> 4;
  const int h = gid & 15;
  const int g = h ^ (row & 7);
  const float* sp = u + (size_t)row * KDIM + g * 8;
  float q = 0.f;
  f16x8 o;
#pragma unroll
  for (int t = 0; t < 8; t++){
    float th = tanhf(sp[t]);
    float sg = (th > 0.f) ? 1.f : ((th < 0.f) ? -1.f : 0.f);
    float d = th - sg;
    q += d * d;
    o[t] = (_Float16)th;
  }
  *(f16x8*)(uhswz + (size_t)row * KDIM + h * 8) = o;
  q = waveRedF(q);
  __shared__ float qb[4];
  if ((tid & 63) == 0) qb[tid >> 6] = q;
  __syncthreads();
  if (tid == 0) atomicAdd(&accf[0], qb[0] + qb[1] + qb[2] + qb[3]);
}

// ---------------- inner = uh @ uh^T (f16 MFMA, 128x128 tile, K=128 in one stage) ----------------
__global__ __launch_bounds__(256) void k_mm(const _Float16* __restrict__ A,
    float* __restrict__ out, int row0){
  __shared__ __align__(16) _Float16 As[128 * KDIM];
  __shared__ __align__(16) _Float16 Bs[128 * KDIM];
  const int tid = threadIdx.x;
  const int wav = tid >> 6, lane = tid & 63;
  const int bj = blockIdx.x, bi = blockIdx.y;

  const char* Ag = (const char*)(A + (size_t)(row0 + bi * 128) * KDIM);
  const char* Bg = (const char*)(A + (size_t)(bj * 128) * KDIM);
  char* Asb = (char*)As;
  char* Bsb = (char*)Bs;
#pragma unroll
  for (int t = 0; t < 8; t++){
    const int ub = wav * 8192 + t * 1024;   // wave-uniform LDS base; HW adds lane*16
    __builtin_amdgcn_global_load_lds((as1c_void*)(Ag + ub + lane * 16),
                                     (as3_void*)(Asb + ub), 16, 0, 0);
    __builtin_amdgcn_global_load_lds((as1c_void*)(Bg + ub + lane * 16),
                                     (as3_void*)(Bsb + ub), 16, 0, 0);
  }
  __syncthreads();

  const int quad = lane >> 4, l16 = lane & 15;
  const int wm = (wav >> 1) * 64, wn = (wav & 1) * 64;
  f32x4 acc[4][4];
#pragma unroll
  for (int im = 0; im < 4; im++)
#pragma unroll
    for (int in = 0; in < 4; in++)
      acc[im][in] = (f32x4){0.f, 0.f, 0.f, 0.f};

#pragma unroll
  for (int kb = 0; kb < 4; kb++){
    f16x8 af[4], bf[4];
#pragma unroll
    for (int i = 0; i < 4; i++){
      const int m = wm + i * 16 + l16;
      const int gidx = kb * 4 + quad;                 // 16B-group index within row
      af[i] = *(const f16x8*)(Asb + m * 256 + ((gidx ^ (m & 7)) << 4));
      const int n = wn + i * 16 + l16;
      bf[i] = *(const f16x8*)(Bsb + n * 256 + ((gidx ^ (n & 7)) << 4));
    }
#pragma unroll
    for (int im = 0; im < 4; im++)
#pragma unroll
      for (int in = 0; in < 4; in++)
        acc[im][in] = __builtin_amdgcn_mfma_f32_16x16x32_f16(af[im], bf[in], acc[im][in], 0, 0, 0);
  }

  float* obase = out + (size_t)(bi * 128) * NROW + (size_t)bj * 128;
#pragma unroll
  for (int im = 0; im < 4; im++)
#pragma unroll
    for (int in = 0; in < 4; in++)
#pragma unroll
      for (int r = 0; r < 4; r++){
        const int rl = wm + im * 16 + quad * 4 + r;   // C/D: row=(lane>>4)*4+reg
        const int cl = wn + in * 16 + l16;            //      col=lane&15
        obase[(size_t)rl * NROW + cl] = acc[im][in][r];
      }
}

// ---------------- exact k-th smallest via 4x8-bit LDS radix select ----------------
__device__ unsigned radix_kth_small(const unsigned* arr, int len, int k,
                                    int* hist, unsigned* sb, int tid, int lane, int wav){
  unsigned prefix = 0;
  int kcur = k;
  for (int shift = 24; shift >= 0; shift -= 8){
    hist[tid] = 0;
    __syncthreads();
    unsigned pm = (shift == 24) ? 0u : (0xFFFFFFFFu << (shift + 8));
    for (int t = tid; t < len; t += 256){
      unsigned kv = arr[t];
      if (((kv ^ prefix) & pm) == 0) atomicAdd(&hist[(kv >> shift) & 255], 1);
    }
    __syncthreads();
    if (wav == 0){
      int h[4];
#pragma unroll
      for (int d = 0; d < 4; d++) h[d] = hist[4 * lane + d];
      int part = h[0] + h[1] + h[2] + h[3];
      int psc = part;
#pragma unroll
      for (int o = 1; o < 64; o <<= 1){ int x = __shfl_up(psc, o, 64); if (lane >= o) psc += x; }
      int before = psc - part;                  // count of keys in lower digit groups
      if (before < kcur && kcur <= psc){        // exactly one lane
        int c = before;
#pragma unroll
        for (int d = 0; d < 4; d++){
          if (kcur <= c + h[d]){ sb[0] = (unsigned)(4 * lane + d); sb[1] = (unsigned)(kcur - c); break; }
          c += h[d];
        }
      }
    }
    __syncthreads();
    prefix |= sb[0] << shift;
    kcur = (int)sb[1];
    __syncthreads();
  }
  return prefix;
}

// ---------------- per-row stats + loss (one block per row, whole row in LDS) ----------------
__global__ __launch_bounds__(256) void k_stats(const float* __restrict__ buf,
    const unsigned char* __restrict__ lab, const int* __restrict__ cnt,
    float* __restrict__ accf, int* __restrict__ acci, int row0){
  __shared__ __align__(16) float rowv[NROW];     // 24 KB
  __shared__ __align__(16) unsigned kk[NROW];    // 24 KB  (~key for dissim, 0xFFFFFFFF for sim)
  __shared__ unsigned simk[512];                 // keys of similar values
  __shared__ int hist[256];
  __shared__ float rbuf[16];
  __shared__ unsigned sb[2];
  __shared__ int simCountS;
  __shared__ float statS[2];

  const int tid = threadIdx.x;
  const int lane = tid & 63;
  const int wav = tid >> 6;
  const int row = row0 + blockIdx.x;
  const int myl = lab[row];
  const int n_sim = cnt[myl];
  const int n_dis = NROW - n_sim;
  if (n_dis == 0 || n_sim == 0) return;          // invalid row: contributes nothing
  const int k1 = n_dis - (n_dis * 9) / 10;       // tail count (top-10% dissimilar)
  const int k2 = n_sim - (n_sim * 9) / 10;       // head count (bottom-10% similar)

  if (tid == 0) simCountS = 0;
  __syncthreads();

  // ---- pass A: load row, sums, keys, gather similar ----
  const float4* src = (const float4*)(buf + (size_t)blockIdx.x * NROW);
  const uchar4* lsrc = (const uchar4*)lab;
  float sumS = 0.f, sumDS = 0.f;
  for (int t = tid; t < NROW / 4; t += 256){
    float4 v4 = src[t];
    uchar4 l4 = lsrc[t];
    ((float4*)rowv)[t] = v4;
    float vv[4] = {v4.x, v4.y, v4.z, v4.w};
    unsigned char ll[4] = {l4.x, l4.y, l4.z, l4.w};
    unsigned ko[4];
#pragma unroll
    for (int e = 0; e < 4; e++){
      float v = vv[e];
      if (ll[e] == (unsigned char)myl){
        sumS += v;
        int p = atomicAdd(&simCountS, 1);
        if (p < 512) simk[p] = key_of(v);
        ko[e] = 0xFFFFFFFFu;                     // sentinel (needs NaN to collide: impossible)
      } else {
        sumDS += v;
        ko[e] = ~key_of(v);                      // inverted: k-th smallest == k-th largest value
      }
    }
    ((uint4*)kk)[t] = make_uint4(ko[0], ko[1], ko[2], ko[3]);
  }
  __syncthreads();
  sumS = waveRedF(sumS); sumDS = waveRedF(sumDS);
  if (lane == 0){ rbuf[wav] = sumS; rbuf[4 + wav] = sumDS; }
  __syncthreads();
  sumS = rbuf[0] + rbuf[1] + rbuf[2] + rbuf[3];
  sumDS = rbuf[4] + rbuf[5] + rbuf[6] + rbuf[7];
  __syncthreads();

  // ---- dMax: k1-th largest dissimilar, tie-exact tail sum ----
  const unsigned kkp = radix_kth_small(kk, NROW, k1, hist, sb, tid, lane, wav);
  float sgt = 0.f, cgt = 0.f;
  for (int t = tid; t < NROW; t += 256){
    unsigned kv = kk[t];
    if (kv < kkp){ sgt += rowv[t]; cgt += 1.f; }
  }
  sgt = waveRedF(sgt); cgt = waveRedF(cgt);
  if (lane == 0){ rbuf[wav] = sgt; rbuf[4 + wav] = cgt; }
  __syncthreads();
  sgt = rbuf[0] + rbuf[1] + rbuf[2] + rbuf[3];
  cgt = rbuf[4] + rbuf[5] + rbuf[6] + rbuf[7];
  __syncthreads();
  const float dSum = sgt + ((float)k1 - cgt) * key_dec(~kkp);

  // ---- sMin: k2-th smallest similar ----
  const int ns = simCountS;
  const unsigned kp2 = radix_kth_small(simk, ns, k2, hist, sb, tid, lane, wav);
  float s2 = 0.f, c2 = 0.f;
  for (int t = tid; t < ns; t += 256){
    unsigned kv = simk[t];
    if (kv < kp2){ s2 += key_dec(kv); c2 += 1.f; }
  }
  s2 = waveRedF(s2); c2 = waveRedF(c2);
  if (lane == 0){ rbuf[wav] = s2; rbuf[4 + wav] = c2; }
  __syncthreads();
  s2 = rbuf[0] + rbuf[1] + rbuf[2] + rbuf[3];
  c2 = rbuf[4] + rbuf[5] + rbuf[6] + rbuf[7];
  __syncthreads();
  const float sSum = s2 + ((float)k2 - c2) * key_dec(kp2);

  if (tid == 0){
    float meanS = fminf(fmaxf(sumS / fmaxf((float)n_sim, 1.f), 0.f), UBV);
    float meanDS = fminf(fmaxf(sumDS / fmaxf((float)n_dis, 1.f), 0.f), UBV);
    float dMax = fminf(fmaxf(dSum / fmaxf((float)k1, 1.f), 0.f), UBV);
    float sMin = fminf(fmaxf(sSum / fmaxf((float)k2, 1.f), 0.f), UBV);
    statS[0] = meanS - (UBV - meanS) / UBV * fabsf(meanS - dMax);   // BP
    statS[1] = meanDS + meanDS / UBV * fabsf(meanDS - sMin);        // BPd
  }
  __syncthreads();

  // ---- loss pass ----
  const float BP = statS[0], BPd = statS[1];
  float ap = 0.f, an = 0.f, cp = 0.f, cn = 0.f;
  for (int t = tid; t < NROW; t += 256){
    float v = rowv[t];
    bool sim = (kk[t] == 0xFFFFFFFFu);
    if (sim){
      if (v != BP){
        float dc = v - BP;
        float f = (v > BP) ? C_COEF * dc : (2.f * C_COEF) * dc;
        ap += softplus_f(f); cp += 1.f;
      }
    } else {
      if (v != BPd){
        float dcd = v - BPd;
        float f = (v < BPd) ? C_COEF * dcd : (2.f * C_COEF) * dcd;
        an += softplus_f(-f); cn += 1.f;
      }
    }
  }
  ap = waveRedF(ap); an = waveRedF(an); cp = waveRedF(cp); cn = waveRedF(cn);
  if (lane == 0){ rbuf[wav] = ap; rbuf[4 + wav] = an; rbuf[8 + wav] = cp; rbuf[12 + wav] = cn; }
  __syncthreads();
  if (tid == 0){
    ap = rbuf[0] + rbuf[1] + rbuf[2] + rbuf[3];
    an = rbuf[4] + rbuf[5] + rbuf[6] + rbuf[7];
    cp = rbuf[8] + rbuf[9] + rbuf[10] + rbuf[11];
    cn = rbuf[12] + rbuf[13] + rbuf[14] + rbuf[15];
    atomicAdd(&accf[1], ap / fmaxf(cp, 1.f));
    atomicAdd(&accf[2], an / fmaxf(cn, 1.f));
    atomicAdd(&acci[3], 1);
  }
}

__global__ void k_final(const float* __restrict__ accf, const int* __restrict__ acci,
                        float* __restrict__ out){
  if (threadIdx.x == 0 && blockIdx.x == 0){
    int c = acci[3];
    float posL = 0.f, navL = 0.f;
    if (c > 0){ posL = accf[1] / (float)c; navL = accf[2] / (float)c; }
    out[0] = posL + navL + 0.1f * (accf[0] / (float)(NROW * KDIM));
  }
}

extern "C" void kernel_launch(void* const* d_in, const int* in_sizes, int n_in,
                              void* d_out, int out_size, void* d_ws, size_t ws_size,
                              hipStream_t stream){
  const float* u = (const float*)d_in[0];
  const int* y = (const int*)d_in[1];
  char* ws = (char*)d_ws;
  float* accf = (float*)ws;                       // [0]=qSum [1]=posSum [2]=negSum
  int* acci = (int*)ws;                           // [3]=validCount
  int* cnt = (int*)(ws + 64);                     // 256 ints
  unsigned char* lab = (unsigned char*)(ws + 4096);
  _Float16* uhswz = (_Float16*)(ws + 16384);
  const size_t ibufOff = 16384 + (size_t)NROW * KDIM * 2;   // 1589248, 16B aligned
  float* ibuf = (float*)(ws + ibufOff);

  hipMemsetAsync(d_ws, 0, 4096, stream);          // accumulators + label histogram
  k_label<<<NROW, 256, 0, stream>>>(y, lab, cnt);
  k_tanh<<<(NROW * 16) / 256, 256, 0, stream>>>(u, uhswz, accf);

  size_t avail = (ws_size > ibufOff) ? ws_size - ibufOff : 0;
  long maxRows = (long)(avail / ((size_t)NROW * 4));
  maxRows = (maxRows / 128) * 128;
  if (maxRows > NROW) maxRows = NROW;
  if (maxRows < 128) maxRows = 128;

  for (int r0 = 0; r0 < NROW; r0 += (int)maxRows){
    int rows = NROW - r0;
    if (rows > maxRows) rows = (int)maxRows;
    k_mm<<<dim3(48, rows / 128), 256, 0, stream>>>(uhswz, ibuf, r0);
    k_stats<<<rows, 256, 0, stream>>>(ibuf, lab, cnt, accf, acci, r0);
  }
  k_final<<<1, 64, 0, stream>>>(accf, acci, (float*)d_out);
}